// Round 1
// baseline (175.203 us; speedup 1.0000x reference)
//
#include <hip/hip_runtime.h>
#include <math.h>

#define NTOK 16384
#define DDIM 2048
#define NEXP 64
#define KC 64
#define MT 64
#define LSTR 68   // padded LDS stride (floats): breaks power-of-2 bank aliasing

// workspace layout (floats): [0..63] f counts, [64..127] P sums, [128] sum lse^2
__global__ void zero_acc(float* acc) {
    int t = threadIdx.x;
    if (t < 129) acc[t] = 0.0f;
}

__global__ __launch_bounds__(256) void gate_main(
    const float* __restrict__ x, const float* __restrict__ W,
    const float* __restrict__ bias, float* __restrict__ out,
    float* __restrict__ acc)
{
    __shared__ __align__(16) float xs[MT * LSTR];   // 64 tokens x 64 k (padded)
    __shared__ __align__(16) float wsm[KC * LSTR];  // 64 k x 64 experts (padded)
    __shared__ int f_loc[NEXP];

    const int tid  = threadIdx.x;
    const int tok0 = blockIdx.x * MT;

    const int tx = tid & 15;          // expert group (4 experts)
    const int ty = tid >> 4;          // token group  (4 tokens)
    const int srow = tid >> 2;        // staging row 0..63
    const int scol = (tid & 3) << 4;  // staging col {0,16,32,48}

    if (tid < NEXP) f_loc[tid] = 0;

    float accr[4][4];
    #pragma unroll
    for (int t = 0; t < 4; ++t)
        #pragma unroll
        for (int j = 0; j < 4; ++j) accr[t][j] = 0.0f;

    const float* xg = x + (size_t)(tok0 + srow) * DDIM + scol;
    const float* wg = W + (size_t)srow * NEXP + scol;

    float4 px[4], pw[4];
    #pragma unroll
    for (int i = 0; i < 4; ++i) {
        px[i] = *(const float4*)(xg + i * 4);
        pw[i] = *(const float4*)(wg + i * 4);
    }

    const int NCH = DDIM / KC;  // 32
    for (int c = 0; c < NCH; ++c) {
        __syncthreads();  // previous chunk's compute done reading LDS
        #pragma unroll
        for (int i = 0; i < 4; ++i) {
            *(float4*)&xs[srow * LSTR + scol + i * 4]  = px[i];
            *(float4*)&wsm[srow * LSTR + scol + i * 4] = pw[i];
        }
        __syncthreads();
        if (c + 1 < NCH) {
            const float* xg2 = xg + (c + 1) * KC;
            const float* wg2 = wg + (size_t)(c + 1) * KC * NEXP;
            #pragma unroll
            for (int i = 0; i < 4; ++i) {
                px[i] = *(const float4*)(xg2 + i * 4);
                pw[i] = *(const float4*)(wg2 + i * 4);
            }
        }
        // compute: 64 tokens x 64 experts x 64 k per block
        #pragma unroll
        for (int kk = 0; kk < KC; kk += 4) {
            float xv[4][4], wv[4][4];
            #pragma unroll
            for (int t = 0; t < 4; ++t)
                *(float4*)xv[t] = *(const float4*)&xs[(ty * 4 + t) * LSTR + kk];
            #pragma unroll
            for (int r = 0; r < 4; ++r)
                *(float4*)wv[r] = *(const float4*)&wsm[(kk + r) * LSTR + tx * 4];
            #pragma unroll
            for (int t = 0; t < 4; ++t)
                #pragma unroll
                for (int r = 0; r < 4; ++r)
                    #pragma unroll
                    for (int j = 0; j < 4; ++j)
                        accr[t][j] = fmaf(xv[t][r], wv[r][j], accr[t][j]);
        }
    }

    // ---- epilogue ----
    __syncthreads();  // done reading xs/wsm; reuse xs as logits [64][LSTR]
    float bb[4];
    *(float4*)bb = *(const float4*)&bias[tx * 4];
    #pragma unroll
    for (int t = 0; t < 4; ++t) {
        float o[4];
        #pragma unroll
        for (int j = 0; j < 4; ++j) o[j] = accr[t][j] + bb[j];
        *(float4*)&xs[(ty * 4 + t) * LSTR + tx * 4] = *(float4*)o;
    }
    __syncthreads();

    if (tid < MT) {  // one thread per token; threads 0..63 = wave 0
        const int t = tid;
        float* row = &xs[t * LSTR];
        float mx = -INFINITY;
        for (int e = 0; e < NEXP; ++e) mx = fmaxf(mx, row[e]);
        float v1 = -INFINITY, v2 = -INFINITY;
        int i1 = 0, i2 = 0;
        float denom = 0.0f;
        for (int e = 0; e < NEXP; ++e) {
            float l = row[e];
            float s = __expf(l - mx);
            row[e] = s;
            denom += s;
            if (l > v1) { v2 = v1; i2 = i1; v1 = l; i1 = e; }
            else if (l > v2) { v2 = l; i2 = e; }
        }
        float s1 = row[i1], s2 = row[i2];
        float cs = s1 + s2;
        const int gt = tok0 + t;
        out[2 * gt]     = (float)i1;
        out[2 * gt + 1] = (float)i2;
        out[2 * NTOK + 2 * gt]     = s1 / cs;
        out[2 * NTOK + 2 * gt + 1] = s2 / cs;
        float inv = 1.0f / denom;
        float zs = 0.0f;
        for (int e = 0; e < NEXP; ++e) {
            float sc = row[e] * inv;
            row[e] = sc;                 // normalized score for P column sums
            zs += __expf(sc);
        }
        float lse = __logf(zs);
        float l2 = lse * lse;
        #pragma unroll
        for (int off = 32; off > 0; off >>= 1) l2 += __shfl_down(l2, off);
        if (t == 0) atomicAdd(&acc[128], l2);
        atomicAdd(&f_loc[i1], 1);
    }
    __syncthreads();

    // P column sums: 256 threads, 4 partial sums per expert
    {
        const int e = tid & 63;
        const int q = tid >> 6;
        float ps = 0.0f;
        #pragma unroll
        for (int t2 = q * 16; t2 < q * 16 + 16; ++t2) ps += xs[t2 * LSTR + e];
        atomicAdd(&acc[64 + e], ps);
    }
    if (tid < NEXP && f_loc[tid] != 0) atomicAdd(&acc[tid], (float)f_loc[tid]);
}

__global__ void gate_finalize(const float* __restrict__ acc, float* __restrict__ out) {
    int e = threadIdx.x;  // 64 threads
    float v = acc[e] * acc[64 + e];
    #pragma unroll
    for (int off = 32; off > 0; off >>= 1) v += __shfl_down(v, off);
    if (e == 0) {
        const float NT = (float)NTOK;
        out[2 * NTOK * 2]     = 0.01f * (v / (float)NEXP) / (NT * NT);
        out[2 * NTOK * 2 + 1] = 0.1f * acc[128] / NT;
    }
}

extern "C" void kernel_launch(void* const* d_in, const int* in_sizes, int n_in,
                              void* d_out, int out_size, void* d_ws, size_t ws_size,
                              hipStream_t stream) {
    const float* x    = (const float*)d_in[0];
    const float* W    = (const float*)d_in[1];
    const float* bias = (const float*)d_in[2];
    float* out = (float*)d_out;
    float* acc = (float*)d_ws;

    zero_acc<<<1, 256, 0, stream>>>(acc);
    gate_main<<<NTOK / MT, 256, 0, stream>>>(x, W, bias, out, acc);
    gate_finalize<<<1, 64, 0, stream>>>(acc, out);
}